// Round 14
// baseline (224.139 us; speedup 1.0000x reference)
//
#include <hip/hip_runtime.h>
#include <hip/hip_bf16.h>
#include <hip/hip_fp16.h>
#include <math.h>

#define B_ 4
#define L_ 1024
#define H_ 8
#define E_ 64
#define N_ 1024
#define NF_ 513            // rfft bins for N=1024
#define SCALE_ 0.125f      // 1/sqrt(E)
#define HE_ (H_ * E_)
#define ZP_ 1104           // padded float2 slots for 1024 points (k_vfft FFT)
#define NBPAD_ 576         // padded bin count: 36 ntiles, 9 per wave
#define SIMP_ 1032         // sim tile row stride in f16 (1024 + 8 pad)

typedef _Float16 f16x8 __attribute__((ext_vector_type(8)));
typedef _Float16 f16x4 __attribute__((ext_vector_type(4)));
typedef float f32x4 __attribute__((ext_vector_type(4)));

// ---------- helpers for k_vfft (round-12 FFT machinery, unchanged) ----------
__device__ __forceinline__ int dr4(int x) {
    const int r = (int)(__brev((unsigned)x) >> 22);
    return ((r & 0x155) << 1) | ((r >> 1) & 0x155);
}
__device__ __forceinline__ int PD(int i) { return i + (i >> 4) + (i >> 6); }
__device__ __forceinline__ float2 cmulw(float2 v, float2 w, float dir) {
    const float wi = dir * w.y;
    return make_float2(v.x * w.x - v.y * wi, v.x * wi + v.y * w.x);
}
__device__ __forceinline__ void r4c(const float2 x0, const float2 x1,
                                    const float2 x2, const float2 x3,
                                    const float dir,
                                    float2& y0, float2& y1, float2& y2, float2& y3) {
    const float ax = x0.x + x2.x, ay = x0.y + x2.y;
    const float bx = x0.x - x2.x, by = x0.y - x2.y;
    const float cx = x1.x + x3.x, cy = x1.y + x3.y;
    const float dx = x1.x - x3.x, dy = x1.y - x3.y;
    y0 = make_float2(ax + cx, ay + cy);
    y2 = make_float2(ax - cx, ay - cy);
    y1 = make_float2(bx - dir * dy, by + dir * dx);
    y3 = make_float2(bx + dir * dy, by - dir * dx);
}
__device__ __forceinline__ void fill_tw(float2* tw, int t) {
    for (int i = t; i < 1024; i += 256) {
        float sv, cv;
        sincosf(6.283185307179586f * (float)i / 1024.0f, &sv, &cv);
        tw[PD(i)] = make_float2(cv, sv);
    }
}
__device__ __forceinline__ void wfft_dit4(float2* z, const float2* tw, int lane, float dir) {
    #pragma unroll
    for (int st = 0; st < 5; ++st) {
        const int l2q = 2 * st, qs = 1 << l2q;
        const int step = 1 << (8 - l2q);
        #pragma unroll
        for (int ib = 0; ib < 4; ++ib) {
            const int j = (st == 0) ? (((lane & 15) << 2) | (lane >> 4)) + 64 * ib
                                    : lane + 64 * ib;
            const int pos = j & (qs - 1);
            const int base = ((j >> l2q) << (l2q + 2)) + pos;
            const int i0 = PD(base), i1 = PD(base + qs), i2 = PD(base + 2 * qs), i3 = PD(base + 3 * qs);
            float2 x0 = z[i0], x1 = z[i1], x2 = z[i2], x3 = z[i3];
            if (st) {
                x1 = cmulw(x1, tw[PD(pos * step)], dir);
                x2 = cmulw(x2, tw[PD(2 * pos * step)], dir);
                x3 = cmulw(x3, tw[PD(3 * pos * step)], dir);
            }
            float2 y0, y1, y2, y3;
            r4c(x0, x1, x2, x3, dir, y0, y1, y2, y3);
            z[i0] = y0; z[i1] = y1; z[i2] = y2; z[i3] = y3;
        }
        __builtin_amdgcn_wave_barrier();
    }
}
__device__ __forceinline__ void wfft_dif4(float2* z, const float2* tw, int lane, float dir) {
    #pragma unroll
    for (int st = 4; st >= 0; --st) {
        const int l2q = 2 * st, qs = 1 << l2q;
        const int step = 1 << (8 - l2q);
        #pragma unroll
        for (int ib = 0; ib < 4; ++ib) {
            const int j = (st == 0) ? (((lane & 15) << 2) | (lane >> 4)) + 64 * ib
                                    : lane + 64 * ib;
            const int pos = j & (qs - 1);
            const int base = ((j >> l2q) << (l2q + 2)) + pos;
            const int i0 = PD(base), i1 = PD(base + qs), i2 = PD(base + 2 * qs), i3 = PD(base + 3 * qs);
            const float2 x0 = z[i0], x1 = z[i1], x2 = z[i2], x3 = z[i3];
            float2 s0, s1, s2, s3;
            r4c(x0, x1, x2, x3, dir, s0, s1, s2, s3);
            if (st) {
                s1 = cmulw(s1, tw[PD(pos * step)], dir);
                s2 = cmulw(s2, tw[PD(2 * pos * step)], dir);
                s3 = cmulw(s3, tw[PD(3 * pos * step)], dir);
            }
            z[i0] = s0; z[i1] = s1; z[i2] = s2; z[i3] = s3;
        }
        __builtin_amdgcn_wave_barrier();
    }
}

// Kernel A: cosine table Cc[bin][s] = cos(2*pi*bin*s/1024), f16, bins>512 zero.
__global__ __launch_bounds__(256) void k_ccos(_Float16* __restrict__ Cc) {
    const int bin = blockIdx.x;            // 0..575
    const int t = threadIdx.x;
    f16x4 o;
    if (bin > 512) {
        o[0] = o[1] = o[2] = o[3] = (_Float16)0.0f;
    } else {
        #pragma unroll
        for (int j = 0; j < 4; ++j) {
            const int s = 4 * t + j;
            const int m = (bin * s) & 1023;          // exact angle reduction
            o[j] = (_Float16)cosf((float)m * 0.006135923151542565f);  // 2pi/1024
        }
    }
    *(f16x4*)(Cc + (size_t)bin * 1024 + 4 * t) = o;
}

// Kernel 0: K rows -> unit-normalized f16 (Kh).
__global__ __launch_bounds__(256) void k_prep(const float* __restrict__ K,
                                              _Float16* __restrict__ Kh) {
    const int i = blockIdx.x * 256 + threadIdx.x;
    if (i >= B_ * L_ * H_) return;
    const float* p = K + (size_t)i * E_;
    float ss = 0.0f;
    #pragma unroll
    for (int j = 0; j < 16; ++j) {
        const float4 v = *(const float4*)(p + j * 4);
        ss += v.x * v.x + v.y * v.y + v.z * v.z + v.w * v.w;
    }
    const float r = rsqrtf(ss);
    _Float16* out = Kh + (size_t)i * E_;
    #pragma unroll
    for (int e = 0; e < E_; e += 8) {
        const float4 x = *(const float4*)(p + e);
        const float4 y = *(const float4*)(p + e + 4);
        f16x8 o;
        o[0] = (_Float16)(x.x * r); o[1] = (_Float16)(x.y * r);
        o[2] = (_Float16)(x.z * r); o[3] = (_Float16)(x.w * r);
        o[4] = (_Float16)(y.x * r); o[5] = (_Float16)(y.y * r);
        o[6] = (_Float16)(y.z * r); o[7] = (_Float16)(y.w * r);
        *(f16x8*)(out + e) = o;
    }
}

// ---- phase-2 group: NU ntiles x 2 m-subtiles, K=1024 (32 ksteps).
// A = Ccos rows (global/L2, reused across m), B = sim tile (LDS, shared across NU).
template<int NU>
__device__ __forceinline__ void qk_group(const _Float16* __restrict__ Cc,
                                         const _Float16* __restrict__ s_sim,
                                         int ntb, int c, int g,
                                         float F0a, float F0b,
                                         float& rs0, float& rs1,
                                         __half2 (&e)[NU * 4]) {
    f32x4 acc[2][NU];
    #pragma unroll
    for (int u = 0; u < NU; ++u) {
        acc[0][u] = (f32x4){0.f, 0.f, 0.f, 0.f};
        acc[1][u] = (f32x4){0.f, 0.f, 0.f, 0.f};
    }
    #pragma unroll 4
    for (int kt = 0; kt < 32; ++kt) {
        const int ko = kt * 32 + g * 8;
        const f16x8 B0 = *(const f16x8*)(s_sim + (size_t)c * SIMP_ + ko);
        const f16x8 B1 = *(const f16x8*)(s_sim + (size_t)(16 + c) * SIMP_ + ko);
        #pragma unroll
        for (int u = 0; u < NU; ++u) {
            const f16x8 A = *(const f16x8*)(Cc + (size_t)((ntb + u) * 16 + c) * 1024 + ko);
            acc[0][u] = __builtin_amdgcn_mfma_f32_16x16x32_f16(A, B0, acc[0][u], 0, 0, 0);
            acc[1][u] = __builtin_amdgcn_mfma_f32_16x16x32_f16(A, B1, acc[1][u], 0, 0, 0);
        }
    }
    #pragma unroll
    for (int u = 0; u < NU; ++u) {
        #pragma unroll
        for (int r = 0; r < 4; ++r) {
            const int bin = (ntb + u) * 16 + 4 * g + r;
            const float e0 = __expf(SCALE_ * (acc[0][u][r] - F0a));
            const float e1 = __expf(SCALE_ * (acc[1][u][r] - F0b));
            if (bin <= 512) { rs0 += e0; rs1 += e1; }
            e[u * 4 + r] = __floats2half2_rn(e0, e1);
        }
    }
}

template<int NU>
__device__ __forceinline__ void qk_accum(float* __restrict__ Gp,
                                         const __half2 (&e)[NU * 4],
                                         int ntb, int c, int g,
                                         float inva, float invb) {
    #pragma unroll
    for (int u = 0; u < NU; ++u) {
        #pragma unroll
        for (int r = 0; r < 4; ++r) {
            const int bin = (ntb + u) * 16 + 4 * g + r;
            const float2 ef = __half22float2(e[u * 4 + r]);
            float v = ef.x * inva + ef.y * invb;
            v += __shfl_xor(v, 1);
            v += __shfl_xor(v, 2);
            v += __shfl_xor(v, 4);
            v += __shfl_xor(v, 8);
            if (c == 0 && bin <= 512) atomicAdd(&Gp[bin], v);
        }
    }
}

// Kernel 1: block = one (b,h) x 32 q-rows, 4 waves. NO FFT.
// Phase 1: MFMA QK^T -> sim=exp(cos) -> f16 tile in LDS; DC rowsums F0 on the
// fly (exact softmax max since sim>0).  Phase 2: ReF = sim @ cos-table via
// MFMA (A=Ccos from L2, reused x2 over m; B=sim from LDS, shared x NU over
// bins); e kept packed in 36 half2 registers (static indexing); rowsums via
// 2 shuffles + small LDS reduce; G via shuffle-reduced atomics.
// Bins padded to 576 -> uniform 9 ntiles/wave; junk bins masked (Ccos rows 0).
__global__ __attribute__((amdgpu_flat_work_group_size(256, 256), amdgpu_waves_per_eu(2, 2)))
void k_qkfft(const float* __restrict__ Q,
             const _Float16* __restrict__ Kh,
             const _Float16* __restrict__ Cc,
             float* __restrict__ G) {
    __shared__ _Float16 s_sim[32 * SIMP_];   // 66.0 KB
    __shared__ float s_F0p[4][32];
    __shared__ float s_F0[32];
    __shared__ float s_rs[4][32];
    __shared__ float s_inv[32];

    const int t = threadIdx.x;
    const int bid = blockIdx.x;
    const int bh = bid >> 5;                 // consecutive blocks share (b,h)
    const int l0 = (bid & 31) * 32;
    const int b = bh >> 3, h = bh & 7;
    const int c = t & 15;
    const int g = (t >> 4) & 3;
    const int w = t >> 6;

    // ---- phase 1: sim = exp(cos-sim), 32 rows x 1024 cols, f16 -> LDS ----
    float p0[2][4];
    #pragma unroll
    for (int m = 0; m < 2; ++m)
        #pragma unroll
        for (int r = 0; r < 4; ++r) p0[m][r] = 0.0f;

    #pragma unroll
    for (int m = 0; m < 2; ++m) {
        const float* qrow = Q + (((size_t)b * L_ + l0 + 16 * m + c) * H_ + h) * E_;
        const float4 x0 = *(const float4*)(qrow + g * 8);
        const float4 y0 = *(const float4*)(qrow + g * 8 + 4);
        const float4 x1 = *(const float4*)(qrow + 32 + g * 8);
        const float4 y1 = *(const float4*)(qrow + 32 + g * 8 + 4);
        float ss = x0.x * x0.x + x0.y * x0.y + x0.z * x0.z + x0.w * x0.w
                 + y0.x * y0.x + y0.y * y0.y + y0.z * y0.z + y0.w * y0.w
                 + x1.x * x1.x + x1.y * x1.y + x1.z * x1.z + x1.w * x1.w
                 + y1.x * y1.x + y1.y * y1.y + y1.z * y1.z + y1.w * y1.w;
        ss += __shfl_xor(ss, 16);
        ss += __shfl_xor(ss, 32);            // lanes {c,c+16,c+32,c+48} share a row
        const float qn = rsqrtf(ss);
        f16x8 af0, af1;
        af0[0] = (_Float16)(x0.x * qn); af0[1] = (_Float16)(x0.y * qn);
        af0[2] = (_Float16)(x0.z * qn); af0[3] = (_Float16)(x0.w * qn);
        af0[4] = (_Float16)(y0.x * qn); af0[5] = (_Float16)(y0.y * qn);
        af0[6] = (_Float16)(y0.z * qn); af0[7] = (_Float16)(y0.w * qn);
        af1[0] = (_Float16)(x1.x * qn); af1[1] = (_Float16)(x1.y * qn);
        af1[2] = (_Float16)(x1.z * qn); af1[3] = (_Float16)(x1.w * qn);
        af1[4] = (_Float16)(y1.x * qn); af1[5] = (_Float16)(y1.y * qn);
        af1[6] = (_Float16)(y1.z * qn); af1[7] = (_Float16)(y1.w * qn);

        #pragma unroll
        for (int i = 0; i < 16; ++i) {
            const int nt = w * 16 + i;
            const f16x8* bp = (const f16x8*)(Kh + (((size_t)b * L_ + nt * 16 + c) * H_ + h) * E_);
            f32x4 acc = (f32x4){0.f, 0.f, 0.f, 0.f};
            acc = __builtin_amdgcn_mfma_f32_16x16x32_f16(af0, bp[g], acc, 0, 0, 0);
            acc = __builtin_amdgcn_mfma_f32_16x16x32_f16(af1, bp[4 + g], acc, 0, 0, 0);
            #pragma unroll
            for (int r = 0; r < 4; ++r) {
                const float ev = __expf(acc[r]);
                p0[m][r] += ev;
                s_sim[(size_t)(16 * m + 4 * g + r) * SIMP_ + nt * 16 + c] = (_Float16)ev;
            }
        }
    }
    // DC rowsums (exact row max of ReF): reduce over cols c
    #pragma unroll
    for (int m = 0; m < 2; ++m)
        #pragma unroll
        for (int r = 0; r < 4; ++r) {
            float v = p0[m][r];
            v += __shfl_xor(v, 1);
            v += __shfl_xor(v, 2);
            v += __shfl_xor(v, 4);
            v += __shfl_xor(v, 8);
            p0[m][r] = v;
        }
    if (c == 0) {
        #pragma unroll
        for (int m = 0; m < 2; ++m)
            #pragma unroll
            for (int r = 0; r < 4; ++r)
                s_F0p[w][16 * m + 4 * g + r] = p0[m][r];
    }
    __syncthreads();
    if (t < 32) s_F0[t] = s_F0p[0][t] + s_F0p[1][t] + s_F0p[2][t] + s_F0p[3][t];
    __syncthreads();

    const float F0a = s_F0[c];
    const float F0b = s_F0[16 + c];

    // ---- phase 2: ReF = sim @ Ccos^T via MFMA; softmax in registers ----
    float rs0 = 0.0f, rs1 = 0.0f;
    __half2 eG0[16], eG1[16], eS[4];
    const int nt0 = w * 9;                    // wave covers bins [144w, 144w+144)
    qk_group<4>(Cc, s_sim, nt0,     c, g, F0a, F0b, rs0, rs1, eG0);
    qk_group<4>(Cc, s_sim, nt0 + 4, c, g, F0a, F0b, rs0, rs1, eG1);
    qk_group<1>(Cc, s_sim, nt0 + 8, c, g, F0a, F0b, rs0, rs1, eS);

    rs0 += __shfl_xor(rs0, 16); rs0 += __shfl_xor(rs0, 32);
    rs1 += __shfl_xor(rs1, 16); rs1 += __shfl_xor(rs1, 32);
    if (g == 0) { s_rs[w][c] = rs0; s_rs[w][16 + c] = rs1; }
    __syncthreads();
    if (t < 32) s_inv[t] = 1.0f / (s_rs[0][t] + s_rs[1][t] + s_rs[2][t] + s_rs[3][t]);
    __syncthreads();
    const float inva = s_inv[c];
    const float invb = s_inv[16 + c];

    float* Gp = G + (size_t)bh * NF_;
    qk_accum<4>(Gp, eG0, nt0,     c, g, inva, invb);
    qk_accum<4>(Gp, eG1, nt0 + 4, c, g, inva, invb);
    qk_accum<1>(Gp, eS,  nt0 + 8, c, g, inva, invb);
}

// Kernel 2: block = one (b,h) x 8 e-channels (4 pairs, one per wave).
// softmax(G)->s_A in-block; per wave: V pair at dr4 slots, wave-private fwd
// FFT, in-place Hermitian*A manipulation, wave-private inverse FFT, write.
__global__ __launch_bounds__(256) void k_vfft(const float* __restrict__ V,
                                              const float* __restrict__ G,
                                              float* __restrict__ Out) {
    __shared__ float2 s_zv[4 * ZP_];
    __shared__ float2 s_tw[ZP_];
    __shared__ float s_A[NF_];
    __shared__ float s_red[8];

    const int t = threadIdx.x;
    const int bid = blockIdx.x;
    const int bh = bid >> 3, pg = bid & 7;
    const int b = bh >> 3, h = bh & 7;
    const int w = t >> 6, lane = t & 63;
    const int e0 = 2 * (pg * 4 + w);

    fill_tw(s_tw, t);

    // ---- softmax(G[bh]) -> s_A (block-cooperative) ----
    {
        const float* Gp = G + (size_t)bh * NF_;
        const float g0 = Gp[t];
        const float g1 = Gp[t + 256];
        const float g2 = (t == 0) ? Gp[512] : -1e30f;
        float m = fmaxf(fmaxf(g0, g1), g2);
        #pragma unroll
        for (int off = 32; off > 0; off >>= 1) m = fmaxf(m, __shfl_xor(m, off));
        if (lane == 0) s_red[w] = m;
        __syncthreads();
        m = fmaxf(fmaxf(s_red[0], s_red[1]), fmaxf(s_red[2], s_red[3]));
        const float p0 = __expf(g0 - m), p1 = __expf(g1 - m);
        const float p2 = (t == 0) ? __expf(g2 - m) : 0.0f;
        float s = p0 + p1 + p2;
        #pragma unroll
        for (int off = 32; off > 0; off >>= 1) s += __shfl_xor(s, off);
        __syncthreads();
        if (lane == 0) s_red[4 + w] = s;
        __syncthreads();
        s = s_red[4] + s_red[5] + s_red[6] + s_red[7];
        const float inv = 1.0f / s;
        s_A[t] = p0 * inv;
        s_A[t + 256] = p1 * inv;
        if (t == 0) s_A[512] = p2 * inv;
    }
    __syncthreads();   // s_A + s_tw ready; no more block barriers

    float2* z = s_zv + w * ZP_;

    #pragma unroll
    for (int jb = 0; jb < 16; ++jb) {
        const int s = lane + 64 * jb;
        const float* vp = V + (((size_t)b * L_ + s) * H_ + h) * E_ + e0;
        z[PD(dr4(s))] = make_float2(vp[0], vp[1]);
    }
    __builtin_amdgcn_wave_barrier();

    wfft_dit4(z, s_tw, lane, -1.0f);   // natural-order X

    // in-place Hermitian manipulation: lane owns (k, 1024-k)
    #pragma unroll
    for (int ib = 0; ib < 8; ++ib) {
        const int k = lane + 64 * ib;
        const int kp = (N_ - k) & (N_ - 1);
        const int ik = PD(k), ikp = PD(kp);
        const float2 X1 = z[ik];
        const float2 X2 = z[ikp];
        const float reV1 = 0.5f * (X1.x + X2.x);
        const float imV1 = 0.5f * (X1.y - X2.y);
        const float reV2 = 0.5f * (X1.y + X2.y);
        const float imV2 = 0.5f * (X2.x - X1.x);
        const float a = s_A[k];
        z[ik] = make_float2(a * reV1 - imV2, imV1 + a * reV2);
        if (kp != k)
            z[ikp] = make_float2(a * reV1 + imV2, -imV1 + a * reV2);
    }
    if (lane == 0) {
        const float2 X = z[PD(512)];
        const float a = s_A[512];
        z[PD(512)] = make_float2(a * X.x, a * X.y);
    }
    __builtin_amdgcn_wave_barrier();

    wfft_dif4(z, s_tw, lane, +1.0f);   // unnormalized inverse, digit-reversed out

    const float invN = 1.0f / (float)N_;
    #pragma unroll
    for (int jb = 0; jb < 16; ++jb) {
        const int p = lane + 64 * jb;
        const int l = dr4(p);
        const float2 r = z[PD(p)];
        const size_t o = (((size_t)b * L_ + l) * E_ + e0) * H_ + h;
        Out[o] = r.x * invN;        // e0   -> Re
        Out[o + H_] = r.y * invN;   // e0+1 -> Im
    }
}

extern "C" void kernel_launch(void* const* d_in, const int* in_sizes, int n_in,
                              void* d_out, int out_size, void* d_ws, size_t ws_size,
                              hipStream_t stream) {
    const float* Q = (const float*)d_in[0];
    const float* K = (const float*)d_in[1];
    const float* V = (const float*)d_in[2];
    float* out = (float*)d_out;

    float* ws = (float*)d_ws;
    float* G      = ws;                                        // 32*513 f32
    _Float16* Kh  = (_Float16*)(ws + B_ * H_ * NF_);           // 2M halves (4 MB)
    _Float16* Cc  = Kh + (size_t)B_ * L_ * H_ * E_;            // 576*1024 halves (1.13 MB)

    hipMemsetAsync(G, 0, (size_t)B_ * H_ * NF_ * sizeof(float), stream);
    k_ccos<<<NBPAD_, 256, 0, stream>>>(Cc);
    k_prep<<<(B_ * L_ * H_ + 255) / 256, 256, 0, stream>>>(K, Kh);
    k_qkfft<<<B_ * H_ * (L_ / 32), 256, 0, stream>>>(Q, Kh, Cc, G);
    k_vfft<<<B_ * H_ * (E_ / 8), 256, 0, stream>>>(V, G, out);
}

// Round 15
// 112.846 us; speedup vs baseline: 1.9862x; 1.9862x over previous
//
#include <hip/hip_runtime.h>
#include <hip/hip_bf16.h>
#include <math.h>

#define B_ 4
#define L_ 1024
#define H_ 8
#define E_ 64
#define N_ 1024
#define NF_ 513            // rfft bins for N=1024
#define SCALE_ 0.125f      // 1/sqrt(E)
#define HE_ (H_ * E_)
#define ZP_ 1104           // padded float2 slots for 1024 points (PD(1023)=1101)

typedef _Float16 f16x8 __attribute__((ext_vector_type(8)));
typedef float f32x4 __attribute__((ext_vector_type(4)));

// base-4 digit reversal of a 10-bit index (5 digits); involution.
__device__ __forceinline__ int dr4(int x) {
    const int r = (int)(__brev((unsigned)x) >> 22);   // bit-reverse 10 bits
    return ((r & 0x155) << 1) | ((r >> 1) & 0x155);   // swap adjacent bits
}

// Padded LDS index (strided-pattern conflict mitigation; b64's residual
// multiplicity is structural -- round-12 lesson).
__device__ __forceinline__ int PD(int i) { return i + (i >> 4) + (i >> 6); }

// w = (cos, sin); multiply v by exp(dir*i*theta).
__device__ __forceinline__ float2 cmulw(float2 v, float2 w, float dir) {
    const float wi = dir * w.y;
    return make_float2(v.x * w.x - v.y * wi, v.x * wi + v.y * w.x);
}

// radix-4 combine: y_q = sum_m x_m * W4^{q*m}, W4 = exp(dir*i*pi/2).
__device__ __forceinline__ void r4c(const float2 x0, const float2 x1,
                                    const float2 x2, const float2 x3,
                                    const float dir,
                                    float2& y0, float2& y1, float2& y2, float2& y3) {
    const float ax = x0.x + x2.x, ay = x0.y + x2.y;
    const float bx = x0.x - x2.x, by = x0.y - x2.y;
    const float cx = x1.x + x3.x, cy = x1.y + x3.y;
    const float dx = x1.x - x3.x, dy = x1.y - x3.y;
    y0 = make_float2(ax + cx, ay + cy);
    y2 = make_float2(ax - cx, ay - cy);
    y1 = make_float2(bx - dir * dy, by + dir * dx);
    y3 = make_float2(bx + dir * dy, by - dir * dx);
}

// Twiddle table at padded slots: tw[PD(k)] = (cos, sin)(2*pi*k/1024).
__device__ __forceinline__ void fill_tw(float2* tw, int t) {
    for (int i = t; i < 1024; i += 256) {
        float sv, cv;
        sincosf(6.283185307179586f * (float)i / 1024.0f, &sv, &cv);
        tw[PD(i)] = make_float2(cv, sv);
    }
}

// ---- Wave-private radix-4 FFT (k_vfft), no s_barrier ----
// Stage 0 uses permuted butterfly assignment (stride-16 addresses).
__device__ __forceinline__ void wfft_dit4(float2* z, const float2* tw, int lane, float dir) {
    #pragma unroll
    for (int st = 0; st < 5; ++st) {
        const int l2q = 2 * st, qs = 1 << l2q;
        const int step = 1 << (8 - l2q);
        #pragma unroll
        for (int ib = 0; ib < 4; ++ib) {
            const int j = (st == 0) ? (((lane & 15) << 2) | (lane >> 4)) + 64 * ib
                                    : lane + 64 * ib;
            const int pos = j & (qs - 1);
            const int base = ((j >> l2q) << (l2q + 2)) + pos;
            const int i0 = PD(base), i1 = PD(base + qs), i2 = PD(base + 2 * qs), i3 = PD(base + 3 * qs);
            float2 x0 = z[i0], x1 = z[i1], x2 = z[i2], x3 = z[i3];
            if (st) {
                x1 = cmulw(x1, tw[PD(pos * step)], dir);
                x2 = cmulw(x2, tw[PD(2 * pos * step)], dir);
                x3 = cmulw(x3, tw[PD(3 * pos * step)], dir);
            }
            float2 y0, y1, y2, y3;
            r4c(x0, x1, x2, x3, dir, y0, y1, y2, y3);
            z[i0] = y0; z[i1] = y1; z[i2] = y2; z[i3] = y3;
        }
        __builtin_amdgcn_wave_barrier();
    }
}

__device__ __forceinline__ void wfft_dif4(float2* z, const float2* tw, int lane, float dir) {
    #pragma unroll
    for (int st = 4; st >= 0; --st) {
        const int l2q = 2 * st, qs = 1 << l2q;
        const int step = 1 << (8 - l2q);
        #pragma unroll
        for (int ib = 0; ib < 4; ++ib) {
            const int j = (st == 0) ? (((lane & 15) << 2) | (lane >> 4)) + 64 * ib
                                    : lane + 64 * ib;
            const int pos = j & (qs - 1);
            const int base = ((j >> l2q) << (l2q + 2)) + pos;
            const int i0 = PD(base), i1 = PD(base + qs), i2 = PD(base + 2 * qs), i3 = PD(base + 3 * qs);
            const float2 x0 = z[i0], x1 = z[i1], x2 = z[i2], x3 = z[i3];
            float2 s0, s1, s2, s3;
            r4c(x0, x1, x2, x3, dir, s0, s1, s2, s3);
            if (st) {
                s1 = cmulw(s1, tw[PD(pos * step)], dir);
                s2 = cmulw(s2, tw[PD(2 * pos * step)], dir);
                s3 = cmulw(s3, tw[PD(3 * pos * step)], dir);
            }
            z[i0] = s0; z[i1] = s1; z[i2] = s2; z[i3] = s3;
        }
        __builtin_amdgcn_wave_barrier();
    }
}

// Kernel 0: K rows -> unit-normalized f16 (Kh); also zeroes G (replaces the
// hipMemsetAsync dispatch).
__global__ __launch_bounds__(256) void k_prep(const float* __restrict__ K,
                                              _Float16* __restrict__ Kh,
                                              float* __restrict__ G) {
    const int i = blockIdx.x * 256 + threadIdx.x;
    if (i < B_ * H_ * NF_) G[i] = 0.0f;
    if (i >= B_ * L_ * H_) return;
    const float* p = K + (size_t)i * E_;
    float ss = 0.0f;
    #pragma unroll
    for (int j = 0; j < 16; ++j) {
        const float4 v = *(const float4*)(p + j * 4);
        ss += v.x * v.x + v.y * v.y + v.z * v.z + v.w * v.w;
    }
    const float r = rsqrtf(ss);
    _Float16* out = Kh + (size_t)i * E_;
    #pragma unroll
    for (int e = 0; e < E_; e += 8) {
        const float4 x = *(const float4*)(p + e);
        const float4 y = *(const float4*)(p + e + 4);
        f16x8 o;
        o[0] = (_Float16)(x.x * r); o[1] = (_Float16)(x.y * r);
        o[2] = (_Float16)(x.z * r); o[3] = (_Float16)(x.w * r);
        o[4] = (_Float16)(y.x * r); o[5] = (_Float16)(y.y * r);
        o[6] = (_Float16)(y.z * r); o[7] = (_Float16)(y.w * r);
        *(f16x8*)(out + e) = o;
    }
}

// Kernel 1 (round-12 best config): block = one (b,h) x 16 q-rows. MFMA QK^T
// (slot j <- K row dr4(j)), then 2 rounds x {scatter 8 rows into FOUR padded
// buffers, block-cooperative quad radix-4 DIT (addressing amortized 4x),
// DC-max softmax (exact row max), s_acc accumulate}.
__global__ __attribute__((amdgpu_flat_work_group_size(256, 256), amdgpu_waves_per_eu(2, 3)))
void k_qkfft(const float* __restrict__ Q,
             const _Float16* __restrict__ Kh,
             float* __restrict__ G) {
    __shared__ float2 s_z[4 * ZP_];   // 4 padded FFT buffers (35.3 KB)
    __shared__ float2 s_tw[ZP_];      // padded twiddles (8.8 KB)
    __shared__ float s_acc[NF_];
    __shared__ float s_red[32];

    const int t = threadIdx.x;
    const int bid = blockIdx.x;
    const int bh = bid >> 6;        // consecutive blocks share (b,h) -> L2 reuse of Kh
    const int chunk = bid & 63;
    const int b = bh >> 3, h = bh & 7;
    const int l0 = chunk * 16;

    const int c = t & 15;           // A-row / B-col within 16-tile
    const int g = (t >> 4) & 3;     // k-group of the fragment / acc row-group
    const int w = t >> 6;           // wave id
    const int lane = t & 63, wid = w;

    fill_tw(s_tw, t);
    for (int kk = t; kk < NF_; kk += 256) s_acc[kk] = 0.0f;

    // ---- A fragments: q-row (l0+c); norm inline (2 shuffles) ----
    const float* qrow = Q + (((size_t)b * L_ + l0 + c) * H_ + h) * E_;
    const float4 x0 = *(const float4*)(qrow + g * 8);
    const float4 y0 = *(const float4*)(qrow + g * 8 + 4);
    const float4 x1 = *(const float4*)(qrow + 32 + g * 8);
    const float4 y1 = *(const float4*)(qrow + 32 + g * 8 + 4);
    float ss = x0.x * x0.x + x0.y * x0.y + x0.z * x0.z + x0.w * x0.w
             + y0.x * y0.x + y0.y * y0.y + y0.z * y0.z + y0.w * y0.w
             + x1.x * x1.x + x1.y * x1.y + x1.z * x1.z + x1.w * x1.w
             + y1.x * y1.x + y1.y * y1.y + y1.z * y1.z + y1.w * y1.w;
    ss += __shfl_xor(ss, 16);
    ss += __shfl_xor(ss, 32);       // lanes {c, c+16, c+32, c+48} share a row
    const float qn = rsqrtf(ss);
    f16x8 af0, af1;
    af0[0] = (_Float16)(x0.x * qn); af0[1] = (_Float16)(x0.y * qn);
    af0[2] = (_Float16)(x0.z * qn); af0[3] = (_Float16)(x0.w * qn);
    af0[4] = (_Float16)(y0.x * qn); af0[5] = (_Float16)(y0.y * qn);
    af0[6] = (_Float16)(y0.z * qn); af0[7] = (_Float16)(y0.w * qn);
    af1[0] = (_Float16)(x1.x * qn); af1[1] = (_Float16)(x1.y * qn);
    af1[2] = (_Float16)(x1.z * qn); af1[3] = (_Float16)(x1.w * qn);
    af1[4] = (_Float16)(y1.x * qn); af1[5] = (_Float16)(y1.y * qn);
    af1[6] = (_Float16)(y1.z * qn); af1[7] = (_Float16)(y1.w * qn);

    // ---- B fragments + MFMA: 16 N-tiles, 2 k-steps each ----
    f32x4 acc[16];
    #pragma unroll
    for (int n = 0; n < 16; ++n) acc[n] = (f32x4){0.0f, 0.0f, 0.0f, 0.0f};

    #pragma unroll
    for (int n = 0; n < 16; ++n) {
        const int j = w * 256 + n * 16 + c;
        const int s = dr4(j);
        const f16x8* bp = (const f16x8*)(Kh + (((size_t)b * L_ + s) * H_ + h) * E_);
        const f16x8 b0 = bp[g];
        const f16x8 b1 = bp[4 + g];
        acc[n] = __builtin_amdgcn_mfma_f32_16x16x32_f16(af0, b0, acc[n], 0, 0, 0);
        acc[n] = __builtin_amdgcn_mfma_f32_16x16x32_f16(af1, b1, acc[n], 0, 0, 0);
        if ((n & 3) == 3) __builtin_amdgcn_sched_barrier(0);  // fence load hoisting
    }

    // sim = exp(cos) in place
    #pragma unroll
    for (int n = 0; n < 16; ++n) {
        #pragma unroll
        for (int r = 0; r < 4; ++r) acc[n][r] = __expf(acc[n][r]);
    }

    const float dir = -1.0f;

    // ---- 2 rounds x (4 concurrent pair-FFTs + fused 8-row softmax) ----
    #pragma unroll
    for (int rr = 0; rr < 2; ++rr) {
        __syncthreads();   // buffers free (prev round reads / init done)
        {
            const int gq = g - 2 * rr;   // rows 8rr..8rr+7 live in g = 2rr, 2rr+1
            if (gq == 0 || gq == 1) {
                float2* z01 = s_z + (2 * gq) * ZP_;
                #pragma unroll
                for (int n = 0; n < 16; ++n) {
                    const int ps = PD(w * 256 + n * 16 + c);
                    z01[ps]       = make_float2(acc[n][0], acc[n][1]);
                    z01[ZP_ + ps] = make_float2(acc[n][2], acc[n][3]);
                }
            }
        }
        __syncthreads();   // scatter visible

        // quad radix-4 DIT (digit-reversed in -> natural out), 5 barriers.
        // st=0: permuted butterfly assignment -> stride-16 addresses.
        #pragma unroll
        for (int st = 0; st < 5; ++st) {
            const int l2q = 2 * st, qs = 1 << l2q;
            const int j = (st == 0) ? (((t & 63) << 2) | (t >> 6)) : t;
            const int pos = j & (qs - 1);
            const int base = ((j >> l2q) << (l2q + 2)) + pos;
            const int i0 = PD(base), i1 = PD(base + qs), i2 = PD(base + 2 * qs), i3 = PD(base + 3 * qs);
            float2 w1, w2, w3;
            if (st) {
                const int step = 1 << (8 - l2q);
                w1 = s_tw[PD(pos * step)];
                w2 = s_tw[PD(2 * pos * step)];
                w3 = s_tw[PD(3 * pos * step)];
            }
            #pragma unroll
            for (int q = 0; q < 4; ++q) {
                float2* z = s_z + q * ZP_;
                float2 a0 = z[i0], a1 = z[i1], a2 = z[i2], a3 = z[i3];
                if (st) { a1 = cmulw(a1, w1, dir); a2 = cmulw(a2, w2, dir); a3 = cmulw(a3, w3, dir); }
                float2 b0, b1, b2, b3;
                r4c(a0, a1, a2, a3, dir, b0, b1, b2, b3);
                z[i0] = b0; z[i1] = b1; z[i2] = b2; z[i3] = b3;
            }
            __syncthreads();
        }

        // extraction: 8 rows; softmax max = DC bin (exact), no max reduce
        const int iT = PD(t), iTn = PD((N_ - t) & (N_ - 1));
        const int iU = PD(t + 256), iUn = PD(768 - t);
        float p[8][2], pm[8], sm[8];
        #pragma unroll
        for (int q = 0; q < 4; ++q) {
            const float2* z = s_z + q * ZP_;
            const float2 X0 = z[iT], X0n = z[iTn], X1 = z[iU], X1n = z[iUn];
            const float2 DC = z[0];                 // PD(0)==0, broadcast
            const float2 XN = z[PD(512)];           // Nyquist bin (used @t0)
            const float mA = SCALE_ * DC.x, mB = SCALE_ * DC.y;
            p[2 * q][0]     = __expf(SCALE_ * 0.5f * (X0.x + X0n.x) - mA);
            p[2 * q][1]     = __expf(SCALE_ * 0.5f * (X1.x + X1n.x) - mA);
            p[2 * q + 1][0] = __expf(SCALE_ * 0.5f * (X0.y + X0n.y) - mB);
            p[2 * q + 1][1] = __expf(SCALE_ * 0.5f * (X1.y + X1n.y) - mB);
            pm[2 * q]     = __expf(SCALE_ * XN.x - mA);
            pm[2 * q + 1] = __expf(SCALE_ * XN.y - mB);
            sm[2 * q]     = p[2 * q][0] + p[2 * q][1] + ((t == 0) ? pm[2 * q] : 0.0f);
            sm[2 * q + 1] = p[2 * q + 1][0] + p[2 * q + 1][1] + ((t == 0) ? pm[2 * q + 1] : 0.0f);
        }
        #pragma unroll
        for (int off = 32; off > 0; off >>= 1) {
            #pragma unroll
            for (int q2 = 0; q2 < 8; ++q2) sm[q2] += __shfl_xor(sm[q2], off);
        }
        if (lane == 0) {
            #pragma unroll
            for (int q2 = 0; q2 < 8; ++q2) s_red[4 * q2 + wid] = sm[q2];
        }
        __syncthreads();
        float add0 = 0.0f, add1 = 0.0f, addm = 0.0f;
        #pragma unroll
        for (int q2 = 0; q2 < 8; ++q2) {
            const float inv = 1.0f / (s_red[4 * q2] + s_red[4 * q2 + 1] +
                                      s_red[4 * q2 + 2] + s_red[4 * q2 + 3]);
            add0 += p[q2][0] * inv;
            add1 += p[q2][1] * inv;
            addm += pm[q2] * inv;
        }
        s_acc[t]       += add0;
        s_acc[t + 256] += add1;
        if (t == 0) s_acc[512] += addm;
    }
    __syncthreads();

    float* Gp = G + (size_t)bh * NF_;
    for (int kk = t; kk < NF_; kk += 256) atomicAdd(&Gp[kk], s_acc[kk]);
}

// Kernel 2: block = one (b,h) x 8 e-channels (4 pairs, one per wave).
// softmax(G)->s_A in-block; per wave: V pair at dr4 slots, wave-private fwd
// FFT, in-place Hermitian*A manipulation, wave-private inverse FFT, write.
__global__ __launch_bounds__(256) void k_vfft(const float* __restrict__ V,
                                              const float* __restrict__ G,
                                              float* __restrict__ Out) {
    __shared__ float2 s_zv[4 * ZP_];
    __shared__ float2 s_tw[ZP_];
    __shared__ float s_A[NF_];
    __shared__ float s_red[8];

    const int t = threadIdx.x;
    const int bid = blockIdx.x;
    const int bh = bid >> 3, pg = bid & 7;
    const int b = bh >> 3, h = bh & 7;
    const int w = t >> 6, lane = t & 63;
    const int e0 = 2 * (pg * 4 + w);

    fill_tw(s_tw, t);

    // ---- softmax(G[bh]) -> s_A (block-cooperative) ----
    {
        const float* Gp = G + (size_t)bh * NF_;
        const float g0 = Gp[t];
        const float g1 = Gp[t + 256];
        const float g2 = (t == 0) ? Gp[512] : -1e30f;
        float m = fmaxf(fmaxf(g0, g1), g2);
        #pragma unroll
        for (int off = 32; off > 0; off >>= 1) m = fmaxf(m, __shfl_xor(m, off));
        if (lane == 0) s_red[w] = m;
        __syncthreads();
        m = fmaxf(fmaxf(s_red[0], s_red[1]), fmaxf(s_red[2], s_red[3]));
        const float p0 = __expf(g0 - m), p1 = __expf(g1 - m);
        const float p2 = (t == 0) ? __expf(g2 - m) : 0.0f;
        float s = p0 + p1 + p2;
        #pragma unroll
        for (int off = 32; off > 0; off >>= 1) s += __shfl_xor(s, off);
        __syncthreads();
        if (lane == 0) s_red[4 + w] = s;
        __syncthreads();
        s = s_red[4] + s_red[5] + s_red[6] + s_red[7];
        const float inv = 1.0f / s;
        s_A[t] = p0 * inv;
        s_A[t + 256] = p1 * inv;
        if (t == 0) s_A[512] = p2 * inv;
    }
    __syncthreads();   // s_A + s_tw ready; no more block barriers

    float2* z = s_zv + w * ZP_;

    #pragma unroll
    for (int jb = 0; jb < 16; ++jb) {
        const int s = lane + 64 * jb;
        const float* vp = V + (((size_t)b * L_ + s) * H_ + h) * E_ + e0;
        z[PD(dr4(s))] = make_float2(vp[0], vp[1]);
    }
    __builtin_amdgcn_wave_barrier();

    wfft_dit4(z, s_tw, lane, -1.0f);   // natural-order X

    // in-place Hermitian manipulation: lane owns (k, 1024-k)
    #pragma unroll
    for (int ib = 0; ib < 8; ++ib) {
        const int k = lane + 64 * ib;
        const int kp = (N_ - k) & (N_ - 1);
        const int ik = PD(k), ikp = PD(kp);
        const float2 X1 = z[ik];
        const float2 X2 = z[ikp];
        const float reV1 = 0.5f * (X1.x + X2.x);
        const float imV1 = 0.5f * (X1.y - X2.y);
        const float reV2 = 0.5f * (X1.y + X2.y);
        const float imV2 = 0.5f * (X2.x - X1.x);
        const float a = s_A[k];
        z[ik] = make_float2(a * reV1 - imV2, imV1 + a * reV2);
        if (kp != k)
            z[ikp] = make_float2(a * reV1 + imV2, -imV1 + a * reV2);
    }
    if (lane == 0) {
        const float2 X = z[PD(512)];
        const float a = s_A[512];
        z[PD(512)] = make_float2(a * X.x, a * X.y);
    }
    __builtin_amdgcn_wave_barrier();

    wfft_dif4(z, s_tw, lane, +1.0f);   // unnormalized inverse, digit-reversed out

    const float invN = 1.0f / (float)N_;
    #pragma unroll
    for (int jb = 0; jb < 16; ++jb) {
        const int p = lane + 64 * jb;
        const int l = dr4(p);
        const float2 r = z[PD(p)];
        const size_t o = (((size_t)b * L_ + l) * E_ + e0) * H_ + h;
        Out[o] = r.x * invN;        // e0   -> Re
        Out[o + H_] = r.y * invN;   // e0+1 -> Im
    }
}

extern "C" void kernel_launch(void* const* d_in, const int* in_sizes, int n_in,
                              void* d_out, int out_size, void* d_ws, size_t ws_size,
                              hipStream_t stream) {
    const float* Q = (const float*)d_in[0];
    const float* K = (const float*)d_in[1];
    const float* V = (const float*)d_in[2];
    float* out = (float*)d_out;

    float* ws = (float*)d_ws;
    float* G     = ws;                                  // B*H*NF floats
    _Float16* Kh = (_Float16*)(ws + B_ * H_ * NF_);     // B*L*H*E halves (4 MB)

    k_prep<<<(B_ * L_ * H_ + 255) / 256, 256, 0, stream>>>(K, Kh, G);
    k_qkfft<<<B_ * H_ * (L_ / 16), 256, 0, stream>>>(Q, Kh, G);
    k_vfft<<<B_ * H_ * (E_ / 8), 256, 0, stream>>>(V, G, out);
}